// Round 1
// baseline (756.570 us; speedup 1.0000x reference)
//
#include <hip/hip_runtime.h>

#define NG    32768
#define NN    128
#define NE    1024
#define NK    32
#define NB    (NG / 2)

// R6: replace {4-bit adjacency-count build + dense 128x128x3 MAC} with a
// sparse edge-order scatter: x staged in LDS as float4/node, agg built with
// no-return ds_add_f32 (3 per edge). Kills ~1280 VALU/wave of mostly-zero
// FMAs and cuts LDS 34.8KB -> 16.1KB per block (occupancy 4 -> 6+ blocks/CU).
// NOTE: aggregation order changes (edge order, atomic) -> absmax no longer
// bit-exact 0; expected ~1e-6 after the two softmaxes.
__global__ __launch_bounds__(256, 6) void dcnn_adj_kernel(
    const float* __restrict__ x,      // (G, N, 3)
    const int*   __restrict__ esrc,   // (G, E)
    const int*   __restrict__ edst,   // (G, E)
    const float* __restrict__ extx,   // (G, K, 3)
    const float* __restrict__ W,      // (3,3)
    const float* __restrict__ M,      // (3,3)
    const float* __restrict__ U,      // (3,3)
    const float* __restrict__ V,      // (3,3)
    const float* __restrict__ W1,     // (6,3)
    const float* __restrict__ b1,     // (3,)
    const float* __restrict__ W2,     // (3,2)
    const float* __restrict__ b2,     // (2,)
    float* __restrict__ out)          // (B, 2)
{
    // per-wave: xs = x rows (float4-padded), agg = scatter accumulator
    __shared__ __attribute__((aligned(16))) float xs[4][NN][4];   // 8 KB
    __shared__ __attribute__((aligned(16))) float ag[4][NN][4];   // 8 KB
    __shared__ float ge[4][3];

    const int t    = threadIdx.x;
    const int w    = t >> 6;
    const int lane = t & 63;
    const int pair = blockIdx.x * 2 + (w >> 1);
    const int g    = (w & 1) ? (pair + NB) : pair;

    const float* __restrict__ xg = x + (size_t)g * (NN * 3);

    // ---- edge lists -> registers (coalesced int4) -------------------------
    const int4* sp = (const int4*)(esrc + (size_t)g * NE);
    const int4* dp = (const int4*)(edst + (size_t)g * NE);
    const int4 s0 = sp[lane], s1 = sp[lane + 64], s2 = sp[lane + 128], s3 = sp[lane + 192];
    const int4 d0 = dp[lane], d1 = dp[lane + 64], d2 = dp[lane + 128], d3 = dp[lane + 192];

    // ext row (lanes 0..31)
    float er0 = 0.f, er1 = 0.f, er2 = 0.f;
    if (lane < NK) {
        const float* ep = extx + (size_t)g * (NK * 3) + lane * 3;
        er0 = ep[0]; er1 = ep[1]; er2 = ep[2];
    }

    // ---- stage x into LDS (2 nodes/lane), zero agg ------------------------
    float* __restrict__ xw = &xs[w][0][0];
    float* __restrict__ aw = &ag[w][0][0];

    const float* p0 = xg + lane * 3;
    const float v0 = p0[0], v1 = p0[1], v2 = p0[2];
    const float* p1 = xg + (lane + 64) * 3;
    const float u0 = p1[0], u1 = p1[1], u2 = p1[2];

    *(float4*)&xw[lane * 4]        = make_float4(v0, v1, v2, 0.f);
    *(float4*)&xw[(lane + 64) * 4] = make_float4(u0, u1, u2, 0.f);
    const float4 z4 = make_float4(0.f, 0.f, 0.f, 0.f);
    *(float4*)&aw[lane * 4]        = z4;
    *(float4*)&aw[(lane + 64) * 4] = z4;

    __builtin_amdgcn_wave_barrier();   // DS ops in-order per wave

    // ---- scatter: per edge, gather x[src] from LDS, 3x ds_add_f32 to dst --
    // 4-edge chunks: 4 gather reads issue ahead of 12 atomics (memory clobber
    // on the atomics keeps zero-stores above and agg-reads below in order).
    #define CHUNK(SA, DA)                                                       \
        {                                                                       \
            const float4 xa = *(const float4*)&xw[(SA).x * 4];                  \
            const float4 xb = *(const float4*)&xw[(SA).y * 4];                  \
            const float4 xc = *(const float4*)&xw[(SA).z * 4];                  \
            const float4 xd = *(const float4*)&xw[(SA).w * 4];                  \
            const unsigned oa = (unsigned)(size_t)&aw[(DA).x * 4];              \
            const unsigned ob = (unsigned)(size_t)&aw[(DA).y * 4];              \
            const unsigned oc = (unsigned)(size_t)&aw[(DA).z * 4];              \
            const unsigned od = (unsigned)(size_t)&aw[(DA).w * 4];              \
            asm volatile("ds_add_f32 %0, %1"          :: "v"(oa), "v"(xa.x) : "memory"); \
            asm volatile("ds_add_f32 %0, %1 offset:4" :: "v"(oa), "v"(xa.y) : "memory"); \
            asm volatile("ds_add_f32 %0, %1 offset:8" :: "v"(oa), "v"(xa.z) : "memory"); \
            asm volatile("ds_add_f32 %0, %1"          :: "v"(ob), "v"(xb.x) : "memory"); \
            asm volatile("ds_add_f32 %0, %1 offset:4" :: "v"(ob), "v"(xb.y) : "memory"); \
            asm volatile("ds_add_f32 %0, %1 offset:8" :: "v"(ob), "v"(xb.z) : "memory"); \
            asm volatile("ds_add_f32 %0, %1"          :: "v"(oc), "v"(xc.x) : "memory"); \
            asm volatile("ds_add_f32 %0, %1 offset:4" :: "v"(oc), "v"(xc.y) : "memory"); \
            asm volatile("ds_add_f32 %0, %1 offset:8" :: "v"(oc), "v"(xc.z) : "memory"); \
            asm volatile("ds_add_f32 %0, %1"          :: "v"(od), "v"(xd.x) : "memory"); \
            asm volatile("ds_add_f32 %0, %1 offset:4" :: "v"(od), "v"(xd.y) : "memory"); \
            asm volatile("ds_add_f32 %0, %1 offset:8" :: "v"(od), "v"(xd.z) : "memory"); \
        }
    CHUNK(s0, d0)
    CHUNK(s1, d1)
    CHUNK(s2, d2)
    CHUNK(s3, d3)
    #undef CHUNK

    // drain the scatter before reading agg (asm hid the dependency)
    asm volatile("s_waitcnt lgkmcnt(0)" ::: "memory");
    __builtin_amdgcn_wave_barrier();

    // ---- read agg for the 2 owned nodes -----------------------------------
    const float4 A0 = *(const float4*)&aw[lane * 4];
    const float4 A1 = *(const float4*)&aw[(lane + 64) * 4];

    // ---- per-node h = relu(xW + aggM), x rows still in registers ----------
    float h0, h1, h2;
    h0 = fmaxf(v0 * W[0] + v1 * W[3] + v2 * W[6] +
               A0.x * M[0] + A0.y * M[3] + A0.z * M[6], 0.f);
    h1 = fmaxf(v0 * W[1] + v1 * W[4] + v2 * W[7] +
               A0.x * M[1] + A0.y * M[4] + A0.z * M[7], 0.f);
    h2 = fmaxf(v0 * W[2] + v1 * W[5] + v2 * W[8] +
               A0.x * M[2] + A0.y * M[5] + A0.z * M[8], 0.f);

    h0 += fmaxf(u0 * W[0] + u1 * W[3] + u2 * W[6] +
                A1.x * M[0] + A1.y * M[3] + A1.z * M[6], 0.f);
    h1 += fmaxf(u0 * W[1] + u1 * W[4] + u2 * W[7] +
                A1.x * M[1] + A1.y * M[4] + A1.z * M[7], 0.f);
    h2 += fmaxf(u0 * W[2] + u1 * W[5] + u2 * W[8] +
                A1.x * M[2] + A1.y * M[5] + A1.z * M[8], 0.f);

    // ---- reduce within 32-lane halves, combine halves via readlane --------
    #pragma unroll
    for (int off = 16; off > 0; off >>= 1) {
        h0  += __shfl_xor(h0,  off);
        h1  += __shfl_xor(h1,  off);
        h2  += __shfl_xor(h2,  off);
        er0 += __shfl_xor(er0, off);
        er1 += __shfl_xor(er1, off);
        er2 += __shfl_xor(er2, off);
    }
    #define RL(v) (__uint_as_float(__builtin_amdgcn_readlane(__float_as_uint(v), 0)) + \
                   __uint_as_float(__builtin_amdgcn_readlane(__float_as_uint(v), 32)))
    const float H0 = RL(h0), H1 = RL(h1), H2 = RL(h2);
    const float E0 = RL(er0), E1 = RL(er1), E2 = RL(er2);
    #undef RL

    // ---- per-wave tail: emb softmax -> ext MLP -> g_emb -------------------
    if (lane == 0) {
        const float mx = fmaxf(H0, fmaxf(H1, H2));
        const float e0 = __expf(H0 - mx), e1 = __expf(H1 - mx), e2 = __expf(H2 - mx);
        const float inv = 1.0f / (e0 + e1 + e2);
        const float emb0 = e0 * inv, emb1 = e1 * inv, emb2 = e2 * inv;

        float ext[3];
        #pragma unroll
        for (int e = 0; e < 3; ++e) {
            const float vv = emb0 * U[e] + emb1 * U[3 + e] + emb2 * U[6 + e]
                           + E0   * V[e] + E1   * V[3 + e] + E2   * V[6 + e];
            ext[e] = fmaxf(vv, 0.f);
        }
        const float mx2 = fmaxf(ext[0], fmaxf(ext[1], ext[2]));
        const float f0 = __expf(ext[0] - mx2), f1 = __expf(ext[1] - mx2), f2 = __expf(ext[2] - mx2);
        const float inv2 = 1.0f / (f0 + f1 + f2);
        ge[w][0] = f0 * inv2; ge[w][1] = f1 * inv2; ge[w][2] = f2 * inv2;
    }

    __syncthreads();

    // ---- pair combine on lane 0 of waves 0 and 2 --------------------------
    if ((w & 1) == 0 && lane == 0) {
        float tt[6];
        tt[0] = ge[w][0] * ge[w + 1][0];
        tt[1] = ge[w][1] * ge[w + 1][1];
        tt[2] = ge[w][2] * ge[w + 1][2];
        tt[3] = ge[w][0] + ge[w + 1][0];
        tt[4] = ge[w][1] + ge[w + 1][1];
        tt[5] = ge[w][2] + ge[w + 1][2];

        float hl[3];
        #pragma unroll
        for (int j = 0; j < 3; ++j) {
            float vv = b1[j];
            #pragma unroll
            for (int i = 0; i < 6; ++i) vv += tt[i] * W1[i * 3 + j];
            hl[j] = fmaxf(vv, 0.f);
        }

        const float l0 = b2[0] + hl[0] * W2[0] + hl[1] * W2[2] + hl[2] * W2[4];
        const float l1 = b2[1] + hl[0] * W2[1] + hl[1] * W2[3] + hl[2] * W2[5];
        const float mm = fmaxf(l0, l1);
        const float q0 = __expf(l0 - mm), q1 = __expf(l1 - mm);
        const float qi = 1.0f / (q0 + q1);
        out[(size_t)pair * 2    ] = q0 * qi;
        out[(size_t)pair * 2 + 1] = q1 * qi;
    }
}

extern "C" void kernel_launch(void* const* d_in, const int* in_sizes, int n_in,
                              void* d_out, int out_size, void* d_ws, size_t ws_size,
                              hipStream_t stream) {
    const float* x    = (const float*)d_in[0];
    const int*   esrc = (const int*)  d_in[1];
    const int*   edst = (const int*)  d_in[2];
    const float* extx = (const float*)d_in[3];
    const float* W    = (const float*)d_in[4];
    const float* M    = (const float*)d_in[5];
    const float* U    = (const float*)d_in[6];
    const float* V    = (const float*)d_in[7];
    const float* W1   = (const float*)d_in[8];
    const float* b1   = (const float*)d_in[9];
    const float* W2   = (const float*)d_in[10];
    const float* b2   = (const float*)d_in[11];
    float* out = (float*)d_out;

    dcnn_adj_kernel<<<NB / 2, 256, 0, stream>>>(
        x, esrc, edst, extx, W, M, U, V, W1, b1, W2, b2, out);
}

// Round 2
// 378.643 us; speedup vs baseline: 1.9981x; 1.9981x over previous
//
#include <hip/hip_runtime.h>

#define NG    32768
#define NN    128
#define NE    1024
#define NK    32
#define NB    (NG / 2)
#define RSTR  17                 // A row stride in dwords (odd -> conflict-free)
#define AWDW  (NN * RSTR)        // 2176 dwords per wave (8.5 KB)

// R7: revert to the R5 dense structure (R6's sparse ds_add_f32 scatter was
// LDS-pipe-bound: 8-bank aliasing + ~100cyc/instr atomic throughput -> 551us).
// Single change vs R5: g is forced through readfirstlane so the dense-loop x
// reads (wave-uniform addresses) become scalar s_load instead of 96 vector
// global loads per lane -- removes their VALU address math, vector issue
// slots, and vmcnt stalls. Numerics identical to R5 (absmax 0).
__global__ __launch_bounds__(256) void dcnn_adj_kernel(
    const float* __restrict__ x,      // (G, N, 3)
    const int*   __restrict__ esrc,   // (G, E)
    const int*   __restrict__ edst,   // (G, E)
    const float* __restrict__ extx,   // (G, K, 3)
    const float* __restrict__ W,      // (3,3)
    const float* __restrict__ M,      // (3,3)
    const float* __restrict__ U,      // (3,3)
    const float* __restrict__ V,      // (3,3)
    const float* __restrict__ W1,     // (6,3)
    const float* __restrict__ b1,     // (3,)
    const float* __restrict__ W2,     // (3,2)
    const float* __restrict__ b2,     // (2,)
    float* __restrict__ out)          // (B, 2)
{
    __shared__ unsigned A[4 * AWDW];  // 34.8 KB
    __shared__ float ge[4][3];

    const int t    = threadIdx.x;
    const int w    = t >> 6;
    const int lane = t & 63;
    const int pair = blockIdx.x * 2 + (w >> 1);
    const int g    = (w & 1) ? (pair + NB) : pair;

    // wave-uniform graph id as an SGPR: makes xg provably uniform so the
    // dense-loop x reads compile to s_load (scalar cache), not vector loads.
    const int gu = __builtin_amdgcn_readfirstlane(g);

    const float* __restrict__ xg = x + (size_t)gu * (NN * 3);

    // ---- edge lists -> registers (coalesced int4) -------------------------
    const int4* sp = (const int4*)(esrc + (size_t)gu * NE);
    const int4* dp = (const int4*)(edst + (size_t)gu * NE);
    const int4 s0 = sp[lane], s1 = sp[lane + 64], s2 = sp[lane + 128], s3 = sp[lane + 192];
    const int4 d0 = dp[lane], d1 = dp[lane + 64], d2 = dp[lane + 128], d3 = dp[lane + 192];

    // ext row (lanes 0..31)
    float er0 = 0.f, er1 = 0.f, er2 = 0.f;
    if (lane < NK) {
        const float* ep = extx + (size_t)gu * (NK * 3) + lane * 3;
        er0 = ep[0]; er1 = ep[1]; er2 = ep[2];
    }

    // ---- zero A (2176 dwords/wave, conflict-free) -------------------------
    unsigned* Aw = &A[w * AWDW];
    #pragma unroll
    for (int i = 0; i < 34; ++i) {
        const int idx = i * 64 + lane;
        if (idx < AWDW) Aw[idx] = 0u;
    }

    __builtin_amdgcn_wave_barrier();   // DS ops in-order per wave

    // ---- build adjacency counts: ONE no-return ds_add_u32 per edge --------
    #define SCAT(SV, DV)                                                    \
        {                                                                   \
            const unsigned off = (unsigned)(size_t)&Aw[(DV) * RSTR + ((SV) >> 3)]; \
            const unsigned val = 1u << (4 * ((SV) & 7));                    \
            asm volatile("ds_add_u32 %0, %1" :: "v"(off), "v"(val) : "memory"); \
        }
    SCAT(s0.x, d0.x) SCAT(s0.y, d0.y) SCAT(s0.z, d0.z) SCAT(s0.w, d0.w)
    SCAT(s1.x, d1.x) SCAT(s1.y, d1.y) SCAT(s1.z, d1.z) SCAT(s1.w, d1.w)
    SCAT(s2.x, d2.x) SCAT(s2.y, d2.y) SCAT(s2.z, d2.z) SCAT(s2.w, d2.w)
    SCAT(s3.x, d3.x) SCAT(s3.y, d3.y) SCAT(s3.z, d3.z) SCAT(s3.w, d3.w)
    #undef SCAT

    // drain the scatter before reading A (asm hid the dependency)
    asm volatile("s_waitcnt lgkmcnt(0)" ::: "memory");
    __builtin_amdgcn_wave_barrier();

    // ---- agg = A @ x : lane owns dst rows {lane, lane+64}, agg in regs ----
    float ac0 = 0.f, ac1 = 0.f, ac2 = 0.f;   // node lane
    float ac3 = 0.f, ac4 = 0.f, ac5 = 0.f;   // node lane+64
    const int r0 = lane * RSTR;
    const int r1 = (lane + 64) * RSTR;

    #pragma unroll
    for (int j = 0; j < 16; ++j) {
        const unsigned da = Aw[r0 + j];
        const unsigned db = Aw[r1 + j];
        // x for srcs j*8 .. j*8+7 : 24 floats, wave-uniform address -> s_load
        float q[24];
        *(float4*)&q[0]  = *(const float4*)(xg + j * 24);
        *(float4*)&q[4]  = *(const float4*)(xg + j * 24 + 4);
        *(float4*)&q[8]  = *(const float4*)(xg + j * 24 + 8);
        *(float4*)&q[12] = *(const float4*)(xg + j * 24 + 12);
        *(float4*)&q[16] = *(const float4*)(xg + j * 24 + 16);
        *(float4*)&q[20] = *(const float4*)(xg + j * 24 + 20);
        #pragma unroll
        for (int o = 0; o < 8; ++o) {
            const float ca = (float)((da >> (4 * o)) & 15u);
            const float cb = (float)((db >> (4 * o)) & 15u);
            const float xs0 = q[o * 3], xs1 = q[o * 3 + 1], xs2 = q[o * 3 + 2];
            ac0 += ca * xs0; ac1 += ca * xs1; ac2 += ca * xs2;
            ac3 += cb * xs0; ac4 += cb * xs1; ac5 += cb * xs2;
        }
    }

    // ---- per-node h = relu(xW + aggM) for the 2 owned nodes ---------------
    float h0, h1, h2;
    {
        const float* xr = xg + lane * 3;
        const float x0 = xr[0], x1 = xr[1], x2 = xr[2];
        h0 = fmaxf(x0 * W[0] + x1 * W[3] + x2 * W[6] +
                   ac0 * M[0] + ac1 * M[3] + ac2 * M[6], 0.f);
        h1 = fmaxf(x0 * W[1] + x1 * W[4] + x2 * W[7] +
                   ac0 * M[1] + ac1 * M[4] + ac2 * M[7], 0.f);
        h2 = fmaxf(x0 * W[2] + x1 * W[5] + x2 * W[8] +
                   ac0 * M[2] + ac1 * M[5] + ac2 * M[8], 0.f);
    }
    {
        const float* xr = xg + (lane + 64) * 3;
        const float x0 = xr[0], x1 = xr[1], x2 = xr[2];
        h0 += fmaxf(x0 * W[0] + x1 * W[3] + x2 * W[6] +
                    ac3 * M[0] + ac4 * M[3] + ac5 * M[6], 0.f);
        h1 += fmaxf(x0 * W[1] + x1 * W[4] + x2 * W[7] +
                    ac3 * M[1] + ac4 * M[4] + ac5 * M[7], 0.f);
        h2 += fmaxf(x0 * W[2] + x1 * W[5] + x2 * W[8] +
                    ac3 * M[2] + ac4 * M[5] + ac5 * M[8], 0.f);
    }

    // ---- reduce within 32-lane halves, combine halves via readlane --------
    #pragma unroll
    for (int off = 16; off > 0; off >>= 1) {
        h0  += __shfl_xor(h0,  off);
        h1  += __shfl_xor(h1,  off);
        h2  += __shfl_xor(h2,  off);
        er0 += __shfl_xor(er0, off);
        er1 += __shfl_xor(er1, off);
        er2 += __shfl_xor(er2, off);
    }
    #define RL(v) (__uint_as_float(__builtin_amdgcn_readlane(__float_as_uint(v), 0)) + \
                   __uint_as_float(__builtin_amdgcn_readlane(__float_as_uint(v), 32)))
    const float H0 = RL(h0), H1 = RL(h1), H2 = RL(h2);
    const float E0 = RL(er0), E1 = RL(er1), E2 = RL(er2);
    #undef RL

    // ---- per-wave tail: emb softmax -> ext MLP -> g_emb -------------------
    if (lane == 0) {
        const float mx = fmaxf(H0, fmaxf(H1, H2));
        const float e0 = __expf(H0 - mx), e1 = __expf(H1 - mx), e2 = __expf(H2 - mx);
        const float inv = 1.0f / (e0 + e1 + e2);
        const float emb0 = e0 * inv, emb1 = e1 * inv, emb2 = e2 * inv;

        float ext[3];
        #pragma unroll
        for (int e = 0; e < 3; ++e) {
            const float vv = emb0 * U[e] + emb1 * U[3 + e] + emb2 * U[6 + e]
                           + E0   * V[e] + E1   * V[3 + e] + E2   * V[6 + e];
            ext[e] = fmaxf(vv, 0.f);
        }
        const float mx2 = fmaxf(ext[0], fmaxf(ext[1], ext[2]));
        const float f0 = __expf(ext[0] - mx2), f1 = __expf(ext[1] - mx2), f2 = __expf(ext[2] - mx2);
        const float inv2 = 1.0f / (f0 + f1 + f2);
        ge[w][0] = f0 * inv2; ge[w][1] = f1 * inv2; ge[w][2] = f2 * inv2;
    }

    __syncthreads();

    // ---- pair combine on lane 0 of waves 0 and 2 --------------------------
    if ((w & 1) == 0 && lane == 0) {
        float tt[6];
        tt[0] = ge[w][0] * ge[w + 1][0];
        tt[1] = ge[w][1] * ge[w + 1][1];
        tt[2] = ge[w][2] * ge[w + 1][2];
        tt[3] = ge[w][0] + ge[w + 1][0];
        tt[4] = ge[w][1] + ge[w + 1][1];
        tt[5] = ge[w][2] + ge[w + 1][2];

        float hl[3];
        #pragma unroll
        for (int j = 0; j < 3; ++j) {
            float vv = b1[j];
            #pragma unroll
            for (int i = 0; i < 6; ++i) vv += tt[i] * W1[i * 3 + j];
            hl[j] = fmaxf(vv, 0.f);
        }

        const float l0 = b2[0] + hl[0] * W2[0] + hl[1] * W2[2] + hl[2] * W2[4];
        const float l1 = b2[1] + hl[0] * W2[1] + hl[1] * W2[3] + hl[2] * W2[5];
        const float mm = fmaxf(l0, l1);
        const float q0 = __expf(l0 - mm), q1 = __expf(l1 - mm);
        const float qi = 1.0f / (q0 + q1);
        out[(size_t)pair * 2    ] = q0 * qi;
        out[(size_t)pair * 2 + 1] = q1 * qi;
    }
}

extern "C" void kernel_launch(void* const* d_in, const int* in_sizes, int n_in,
                              void* d_out, int out_size, void* d_ws, size_t ws_size,
                              hipStream_t stream) {
    const float* x    = (const float*)d_in[0];
    const int*   esrc = (const int*)  d_in[1];
    const int*   edst = (const int*)  d_in[2];
    const float* extx = (const float*)d_in[3];
    const float* W    = (const float*)d_in[4];
    const float* M    = (const float*)d_in[5];
    const float* U    = (const float*)d_in[6];
    const float* V    = (const float*)d_in[7];
    const float* W1   = (const float*)d_in[8];
    const float* b1   = (const float*)d_in[9];
    const float* W2   = (const float*)d_in[10];
    const float* b2   = (const float*)d_in[11];
    float* out = (float*)d_out;

    dcnn_adj_kernel<<<NB / 2, 256, 0, stream>>>(
        x, esrc, edst, extx, W, M, U, V, W1, b1, W2, b2, out);
}